// Round 3
// baseline (268.936 us; speedup 1.0000x reference)
//
#include <hip/hip_runtime.h>

#define CC 384
#define HW 3136            // 56*56
#define WIDTH 56
#define PLANE_ELEMS (CC*HW)  // 1204224
#define EPS 1e-5f

// bf16 x_pw for plane p lives in the 2nd half of plane p's f32 output slot:
// ushort index = p*6272 + 3136 + j   (slot = 12544 B = 6272 ushorts)
#define SLOT_U 6272
#define HALF_U 3136

// Pre-packed W (bf16) in workspace: [12 kt][384 o][40 kk]
#define WROW 40
#define WSTEP_U (CC*WROW)        // 15360 ushorts per k-step = 30720 B
#define WP_TOTAL (12*WSTEP_U)    // 184320 ushorts = 368640 B of d_ws

// Pre-packed Toeplitz B per channel: [c][13 ky][16 n][32 k] bf16
#define BT_U 6656
#define BT_TOTAL (CC*BT_U)       // 2555904 ushorts = 5111808 B

// Kernel A o-split: each block owns 192 of the 384 out-channels.
#define OHALF 192
#define WHALF_U (OHALF*WROW)     // 7680 ushorts = 15360 B = 15 x 1KB chunks

typedef __attribute__((ext_vector_type(8))) short bf16x8;
typedef __attribute__((ext_vector_type(4))) float f32x4;

static __device__ __forceinline__ float bf2f(unsigned short u) {
  union { unsigned int i; float f; } x; x.i = ((unsigned int)u) << 16; return x.f;
}
static __device__ __forceinline__ unsigned short f2bf(float f) {
  union { float f; unsigned int i; } x; x.f = f;
  unsigned int r = x.i + 0x7fffu + ((x.i >> 16) & 1u);
  return (unsigned short)(r >> 16);
}

// ---------------------------------------------------------------------------
// Kernel 0: pre-pack W f32 -> bf16 in k-step-major padded layout.
// ---------------------------------------------------------------------------
__global__ __launch_bounds__(256) void pack_w(
    const float* __restrict__ wmat, unsigned short* __restrict__ wp)
{
  int i = blockIdx.x * 256 + threadIdx.x;      // grid sized exactly
  int kt  = i / WSTEP_U;
  int rem = i - kt * WSTEP_U;
  int o   = rem / WROW;
  int kk  = rem - o * WROW;
  unsigned short v = 0;
  if (kk < 32) v = f2bf(wmat[o * CC + kt * 32 + kk]);
  wp[i] = v;
}

// ---------------------------------------------------------------------------
// Kernel 0b: pre-pack Toeplitz Bt per channel (bf16).
// Bt[c][ky][n][k] = w[c][ky][k-n-2] (matches left-pad-8 tile layout).
// ---------------------------------------------------------------------------
__global__ __launch_bounds__(256) void pack_bt(
    const float* __restrict__ dwkw, unsigned short* __restrict__ btg)
{
  const int c = blockIdx.x;
  for (int i = threadIdx.x; i < BT_U; i += 256) {
    int ky = i >> 9, rem = i & 511, n = rem >> 5, k = rem & 31;
    int kx = k - n - 2;
    unsigned short v = 0;
    if ((unsigned)kx < 13u) v = f2bf(dwkw[c * 169 + ky * 13 + kx]);
    btg[(size_t)c * BT_U + i] = v;
  }
}

// ---------------------------------------------------------------------------
// Kernel A v3: one block = 64 spatial x 192 out-channels (o split in 2).
// Round-2 changes (latency/occupancy-bound: Occ 21%, all pipes <10%):
//  - grid 784 -> 1568 blocks (6.1/CU); LDS 38.9KB -> ~22KB; acc 96 -> 48
//    VGPR. Occupancy cap rises from 3-4 to ~5-6 blocks/CU.
//  - k-loop register pipeline: ds_write current x regs, issue W chunk glds,
//    THEN issue next k-step's x loads; the single barrier drains both
//    concurrently (exposed latency = max(x,W), was x+W serialized).
//  - x staged twice (once per o-half) but stays L3-resident -> HBM flat.
// ---------------------------------------------------------------------------
__global__ __launch_bounds__(256, 5) void pw_gemm_bn_res(
    const float* __restrict__ xin,
    const unsigned short* __restrict__ wp,
    const float* __restrict__ pwg, const float* __restrict__ pwb,
    const float* __restrict__ pwm, const float* __restrict__ pwv,
    unsigned short* __restrict__ xpw)   // = (ushort*)d_out
{
  __shared__ __align__(16) unsigned short Xt[64 * 40];   //  5120 B, [j][k] pad 40
  __shared__ __align__(16) unsigned short Wt[WHALF_U];   // 15360 B, [o][k] pad 40
  __shared__ float scaleS[OHALF];
  __shared__ float shiftS[OHALF];

  const int tid = threadIdx.x;
  const int j0 = blockIdx.x * 64;       // spatial tile (3136 = 49*64)
  const int o0 = blockIdx.y * OHALF;    // o-half
  const int b  = blockIdx.z;
  const size_t bbase = (size_t)b * PLANE_ELEMS;

  if (tid < OHALF) {
    int o = o0 + tid;
    float s = pwg[o] * rsqrtf(pwv[o] + EPS);
    scaleS[tid] = s;
    shiftS[tid] = pwb[o] - pwm[o] * s;
  }

  const int lane = tid & 63;
  const int wid  = tid >> 6;
  const int l15  = lane & 15;
  const int q    = lane >> 4;

  f32x4 acc[4][3] = {};             // static-indexed only (stays in VGPRs)

  // X staging role: this thread loads 8 consecutive k for spatial j0+lane
  const float* xsrc0 = xin + bbase + (size_t)(wid * 8) * HW + (j0 + lane);

  // preload k-step 0 into registers
  float xv[8];
  #pragma unroll
  for (int i = 0; i < 8; ++i) xv[i] = xsrc0[(size_t)i * HW];

  for (int kt = 0; kt < 12; ++kt) {
    __syncthreads();                // previous step's Xt/Wt fully consumed
    // ---- write current x regs into Xt (one conflict-free b128) ----
    {
      bf16x8 u;
      #pragma unroll
      for (int i = 0; i < 8; ++i) u[i] = (short)f2bf(xv[i]);
      *((bf16x8*)&Xt[lane * 40 + wid * 8]) = u;
    }
    // ---- issue W half-tile: 15 x 1KB chunks via global_load_lds ----
    {
      const unsigned short* g = wp + (size_t)kt * WSTEP_U + (size_t)o0 * WROW;
      #pragma unroll
      for (int i = 0; i < 4; ++i) {
        int c = i * 4 + wid;
        if (c < 15) {
          __builtin_amdgcn_global_load_lds(
              (const __attribute__((address_space(1))) unsigned int*)(g + c * 512 + lane * 8),
              (__attribute__((address_space(3))) unsigned int*)(&Wt[c * 512]),
              16, 0, 0);
        }
      }
    }
    // ---- issue next k-step's x loads (overlaps with W latency) ----
    if (kt < 11) {
      const float* src = xsrc0 + (size_t)(kt + 1) * 32 * HW;
      #pragma unroll
      for (int i = 0; i < 8; ++i) xv[i] = src[(size_t)i * HW];
    }
    __syncthreads();                // drains x-prefetch AND W glds together

    bf16x8 a[4];
    #pragma unroll
    for (int jf = 0; jf < 4; ++jf)
      a[jf] = *((const bf16x8*)&Xt[(jf * 16 + l15) * 40 + q * 8]);

    #pragma unroll
    for (int of = 0; of < 3; ++of) {
      bf16x8 bb = *((const bf16x8*)&Wt[(wid * 48 + of * 16 + l15) * WROW + q * 8]);
      #pragma unroll
      for (int jf = 0; jf < 4; ++jf)
        acc[jf][of] = __builtin_amdgcn_mfma_f32_16x16x32_bf16(a[jf], bb, acc[jf][of], 0, 0, 0);
    }
  }

  // ---- epilogue: BN + residual, write bf16 stash ----
  // D layout: col = l15 -> o within 16-frag, row = q*4+r -> j within 16-frag
  const int ob = wid * 48;
  #pragma unroll
  for (int of = 0; of < 3; ++of) {
    const int oo = ob + of * 16 + l15;
    const int o = o0 + oo;
    const float s = scaleS[oo], t = shiftS[oo];
    #pragma unroll
    for (int jf = 0; jf < 4; ++jf) {
      const int j = j0 + jf * 16 + q * 4;
      f32x4 av = acc[jf][of];
      float4 xr = *((const float4*)(xin + bbase + (size_t)o * HW + j));
      ushort4 w4;
      w4.x = f2bf(av[0] * s + t + xr.x);
      w4.y = f2bf(av[1] * s + t + xr.y);
      w4.z = f2bf(av[2] * s + t + xr.z);
      w4.w = f2bf(av[3] * s + t + xr.w);
      size_t pidx = (size_t)(b * CC + o) * SLOT_U + HALF_U + j;
      *((ushort4*)(xpw + pidx)) = w4;
    }
  }
}

// ---------------------------------------------------------------------------
// Kernel B v2 (MFMA Toeplitz): 13x13 depthwise conv + BN_k + center-tap
// branch + exact GELU, one block per (b,c) plane. (unchanged this round)
// ---------------------------------------------------------------------------
#define TSTRIDE 88
#define TROWS 76
#define NCH 11   // b128 chunks per tile row (88 u16 = 11 * 8)

__global__ __launch_bounds__(256) void dw_conv_mfma(
    float* __restrict__ outf,                 // d_out as f32
    const unsigned short* __restrict__ stash, // d_out as ushort (bf16 halves)
    const unsigned short* __restrict__ btg,   // pre-packed Bt (or nullptr)
    const float* __restrict__ dwkw,
    const float* __restrict__ dkg, const float* __restrict__ dkb,
    const float* __restrict__ dkm, const float* __restrict__ dkv,
    const float* __restrict__ d1w,
    const float* __restrict__ d1g, const float* __restrict__ d1b,
    const float* __restrict__ d1m, const float* __restrict__ d1v)
{
  __shared__ __align__(16) unsigned short tile[TROWS * TSTRIDE]; // 13376 B
  __shared__ __align__(16) unsigned short Bt[13 * 16 * 32];      // 13312 B

  const int bc = blockIdx.x;
  const int c = bc % CC;
  const size_t plane_u = (size_t)bc * SLOT_U + HALF_U;  // bf16 stash base
  const size_t plane_f = (size_t)bc * HW;               // f32 out base
  const int tid = threadIdx.x;
  const int lane = tid & 63;
  const int wid  = tid >> 6;

  // ---- stage plane into zero-padded bf16 tile: all-vector b128 writes ----
  // tile[r][col]: col 0..7 zero | col 8..63 = row gy=r-6 | col 64..87 zero
  for (int i = tid; i < TROWS * NCH; i += 256) {
    int r = i / NCH, ch = i - r * NCH;
    int gy = r - 6;
    bf16x8 v = {0,0,0,0,0,0,0,0};
    if ((unsigned)gy < (unsigned)WIDTH && ch >= 1 && ch <= 7)
      v = *((const bf16x8*)(stash + plane_u + gy * WIDTH + (ch - 1) * 8));
    *((bf16x8*)&tile[r * TSTRIDE + ch * 8]) = v;
  }

  // ---- stage Toeplitz Bt ----
  if (btg) {
    const unsigned short* g = btg + (size_t)c * BT_U;
    #pragma unroll
    for (int i = 0; i < 4; ++i) {
      int ch = i * 4 + wid;
      if (ch < 13) {
        __builtin_amdgcn_global_load_lds(
            (const __attribute__((address_space(1))) unsigned int*)(g + ch * 512 + lane * 8),
            (__attribute__((address_space(3))) unsigned int*)(&Bt[ch * 512]),
            16, 0, 0);
      }
    }
  } else {
    for (int i = tid; i < 13 * 512; i += 256) {
      int ky = i >> 9, rem = i & 511, n = rem >> 5, k = rem & 31;
      int kx = k - n - 2;
      float wv = ((unsigned)kx < 13u) ? dwkw[c * 169 + ky * 13 + kx] : 0.f;
      Bt[i] = f2bf(wv);
    }
  }

  const float sk = dkg[c] * rsqrtf(dkv[c] + EPS);
  const float tk = dkb[c] - dkm[c] * sk;
  const float s1 = d1g[c] * rsqrtf(d1v[c] + EPS);
  const float a1 = d1w[c] * s1;
  const float t1 = d1b[c] - d1m[c] * s1;
  const float tsum = tk + t1;

  __syncthreads();

  const int l15  = lane & 15;   // A: m index / D: col (x offset)
  const int q    = lane >> 4;   // A/B: k quad / D: row group

  // hoist B fragments (channel-constant) into registers
  bf16x8 bfr[13];
  #pragma unroll
  for (int ky = 0; ky < 13; ++ky)
    bfr[ky] = *((const bf16x8*)&Bt[(ky * 16 + l15) * 32 + q * 8]);

  // 16 output tiles of 16x16 cover 64x64 >= 56x56; 4 waves -> 4 tiles each
  for (int t = wid; t < 16; t += 4) {
    const int y0 = (t >> 2) * 16, x0 = (t & 3) * 16;
    f32x4 acc = {0.f, 0.f, 0.f, 0.f};
    #pragma unroll
    for (int ky = 0; ky < 13; ++ky) {
      bf16x8 a = *((const bf16x8*)&tile[(y0 + l15 + ky) * TSTRIDE + x0 + q * 8]);
      acc = __builtin_amdgcn_mfma_f32_16x16x32_bf16(a, bfr[ky], acc, 0, 0, 0);
    }
    // epilogue: D row m = q*4+r, col n = l15
    const int x = x0 + l15;
    if (x < WIDTH) {
      #pragma unroll
      for (int r = 0; r < 4; ++r) {
        const int y = y0 + q * 4 + r;
        if (y < WIDTH) {
          float ctr = bf2f(tile[(y + 6) * TSTRIDE + x + 8]);
          float v = acc[r] * sk + tsum + ctr * a1;
          outf[plane_f + y * WIDTH + x] =
              0.5f * v * (1.f + erff(v * 0.70710678118654752f));
        }
      }
    }
  }
}

extern "C" void kernel_launch(void* const* d_in, const int* in_sizes, int n_in,
                              void* d_out, int out_size, void* d_ws, size_t ws_size,
                              hipStream_t stream) {
  const float* x     = (const float*)d_in[0];
  const float* pw_w  = (const float*)d_in[1];
  const float* pw_g  = (const float*)d_in[2];
  const float* pw_b  = (const float*)d_in[3];
  const float* pw_m  = (const float*)d_in[4];
  const float* pw_v  = (const float*)d_in[5];
  const float* dwk_w = (const float*)d_in[6];
  const float* dwk_g = (const float*)d_in[7];
  const float* dwk_b = (const float*)d_in[8];
  const float* dwk_m = (const float*)d_in[9];
  const float* dwk_v = (const float*)d_in[10];
  const float* dw1_w = (const float*)d_in[11];
  const float* dw1_g = (const float*)d_in[12];
  const float* dw1_b = (const float*)d_in[13];
  const float* dw1_m = (const float*)d_in[14];
  const float* dw1_v = (const float*)d_in[15];
  float* outf = (float*)d_out;
  unsigned short* outu = (unsigned short*)d_out;
  unsigned short* wpack = (unsigned short*)d_ws;   // [0, 368640) bytes

  pack_w<<<WP_TOTAL / 256, 256, 0, stream>>>(pw_w, wpack);

  unsigned short* btg = nullptr;
  if (ws_size >= (size_t)(WP_TOTAL + BT_TOTAL) * sizeof(unsigned short)) {
    btg = wpack + WP_TOTAL;
    pack_bt<<<CC, 256, 0, stream>>>(dwk_w, btg);
  }

  dim3 gridA(HW / 64, 2, 16);
  pw_gemm_bn_res<<<gridA, 256, 0, stream>>>(x, wpack, pw_g, pw_b, pw_m, pw_v, outu);

  dim3 gridB(16 * CC);
  dw_conv_mfma<<<gridB, 256, 0, stream>>>(outf, outu, btg, dwk_w,
      dwk_g, dwk_b, dwk_m, dwk_v, dw1_w, dw1_g, dw1_b, dw1_m, dw1_v);
}

// Round 4
// 254.375 us; speedup vs baseline: 1.0572x; 1.0572x over previous
//
#include <hip/hip_runtime.h>

#define CC 384
#define HW 3136            // 56*56
#define WIDTH 56
#define PLANE_ELEMS (CC*HW)  // 1204224
#define EPS 1e-5f

// bf16 x_pw for plane p lives in the 2nd half of plane p's f32 output slot:
// ushort index = p*6272 + 3136 + j   (slot = 12544 B = 6272 ushorts)
#define SLOT_U 6272
#define HALF_U 3136

// ---------------- fast-path workspace layout (ushort units) ----------------
// wf  : W in fragment order  [12 kt][24 og][64 lane][8]      = 147456 u
// btg : Toeplitz B per chan  [384 c][13 ky][16 n][32 k]      = 2555904 u
// xf  : x A-fragments        [16 b][49 jt][12 kt][4 jf][64 lane][8]
#define WF_U (12*24*64*8)          // 147456
#define BT_U 6656
#define BT_TOTAL (CC*BT_U)         // 2555904
#define XF_U (16*49*12*4*64*8)     // 19267584
#define WS_FAST_BYTES ((size_t)(WF_U + BT_TOTAL + XF_U) * 2)   // 43,941,888 B

// ---------------- old-path (fallback) W layout ----------------
#define WROW 40
#define WSTEP_U (CC*WROW)        // 15360 ushorts per k-step
#define WP_TOTAL (12*WSTEP_U)    // 184320 ushorts

typedef __attribute__((ext_vector_type(8))) short bf16x8;
typedef __attribute__((ext_vector_type(4))) float f32x4;

static __device__ __forceinline__ float bf2f(unsigned short u) {
  union { unsigned int i; float f; } x; x.i = ((unsigned int)u) << 16; return x.f;
}
static __device__ __forceinline__ unsigned short f2bf(float f) {
  union { float f; unsigned int i; } x; x.f = f;
  unsigned int r = x.i + 0x7fffu + ((x.i >> 16) & 1u);
  return (unsigned short)(r >> 16);
}

// ---------------------------------------------------------------------------
// pack_wf: W f32 -> bf16 directly in MFMA B-fragment order.
// wf[((kt*24+og)*64+lane)*8+i] = bf16(W[og*16+(lane&15)][kt*32+(lane>>4)*8+i])
// 18432 threads total.
// ---------------------------------------------------------------------------
__global__ __launch_bounds__(256) void pack_wf(
    const float* __restrict__ wmat, unsigned short* __restrict__ wf)
{
  int t = blockIdx.x * 256 + threadIdx.x;     // grid = 72 blocks exactly
  int kt  = t / (24 * 64);
  int rem = t - kt * 24 * 64;
  int og  = rem >> 6;
  int lane = rem & 63;
  int o  = og * 16 + (lane & 15);
  int k0 = kt * 32 + (lane >> 4) * 8;
  bf16x8 u;
  #pragma unroll
  for (int i = 0; i < 8; ++i) u[i] = (short)f2bf(wmat[o * CC + k0 + i]);
  *((bf16x8*)(wf + (size_t)t * 8)) = u;
}

// ---------------------------------------------------------------------------
// pack_bt: pre-pack Toeplitz Bt per channel (bf16). (unchanged)
// Bt[c][ky][n][k] = w[c][ky][k-n-2] (matches left-pad-8 tile layout).
// ---------------------------------------------------------------------------
__global__ __launch_bounds__(256) void pack_bt(
    const float* __restrict__ dwkw, unsigned short* __restrict__ btg)
{
  const int c = blockIdx.x;
  for (int i = threadIdx.x; i < BT_U; i += 256) {
    int ky = i >> 9, rem = i & 511, n = rem >> 5, k = rem & 31;
    int kx = k - n - 2;
    unsigned short v = 0;
    if ((unsigned)kx < 13u) v = f2bf(dwkw[c * 169 + ky * 13 + kx]);
    btg[(size_t)c * BT_U + i] = v;
  }
}

// ---------------------------------------------------------------------------
// stage_xfrag: f32 x -> bf16 A-fragments, one (kt, jt, b) tile per block.
// 9408 blocks (~37/CU) -> pure streaming pass, latency hidden by occupancy.
// Staging + fragment-read pattern identical to the proven v2 kernel.
// ---------------------------------------------------------------------------
__global__ __launch_bounds__(256) void stage_xfrag(
    const float* __restrict__ xin, unsigned short* __restrict__ xf)
{
  __shared__ __align__(16) unsigned short Xt[64 * 40];   // [j][k], pad 40
  const int kt = blockIdx.x, jt = blockIdx.y, b = blockIdx.z;
  const int tid = threadIdx.x;
  const int lane = tid & 63, wid = tid >> 6;
  const int l15 = lane & 15, q = lane >> 4;

  const float* src = xin + (size_t)b * PLANE_ELEMS
                   + (size_t)(kt * 32 + wid * 8) * HW + jt * 64 + lane;
  bf16x8 u;
  #pragma unroll
  for (int i = 0; i < 8; ++i) u[i] = (short)f2bf(src[(size_t)i * HW]);
  *((bf16x8*)&Xt[lane * 40 + wid * 8]) = u;
  __syncthreads();
  bf16x8 f = *((const bf16x8*)&Xt[(wid * 16 + l15) * 40 + q * 8]);  // jf = wid
  *((bf16x8*)(xf + ((size_t)((b * 49 + jt) * 12 + kt) * 4 + wid) * 512
                 + lane * 8)) = f;
}

// ---------------------------------------------------------------------------
// pw_gemm_frag: barrier-free, LDS-free GEMM + BN + residual -> bf16 stash.
// One wave = 64 j x 48 o; block = 256 thr; grid (49 jt, 2 oh, 16 b).
// Per k-step per wave: 4 xf-frag b128 + 3 wf-frag b128 (all 1KB coalesced,
// wf is L2-resident) + 12 MFMA. No syncthreads -> no vmcnt(0) drains; waves
// free-run and keep loads in flight (round-3 lesson: barriers killed BW).
// Accumulation order per (o,j) identical to v2 -> bitwise-same numerics.
// ---------------------------------------------------------------------------
__global__ __launch_bounds__(256, 3) void pw_gemm_frag(
    const float* __restrict__ xin,
    const unsigned short* __restrict__ wf,
    const unsigned short* __restrict__ xf,
    const float* __restrict__ pwg, const float* __restrict__ pwb,
    const float* __restrict__ pwm, const float* __restrict__ pwv,
    unsigned short* __restrict__ xpw)   // = (ushort*)d_out
{
  const int tid = threadIdx.x;
  const int jt = blockIdx.x, oh = blockIdx.y, b = blockIdx.z;
  const int j0 = jt * 64;
  const int lane = tid & 63, wid = tid >> 6;
  const int l15 = lane & 15, q = lane >> 4;
  const size_t bbase = (size_t)b * PLANE_ELEMS;

  f32x4 acc[4][3] = {};

  const unsigned short* xbase = xf + (size_t)(b * 49 + jt) * (12 * 2048) + lane * 8;
  const unsigned short* wbase = wf + lane * 8;
  const int ogb = oh * 12 + wid * 3;

  #pragma unroll 2
  for (int kt = 0; kt < 12; ++kt) {
    bf16x8 a[4];
    #pragma unroll
    for (int jf = 0; jf < 4; ++jf)
      a[jf] = *((const bf16x8*)(xbase + (kt * 4 + jf) * 512));
    #pragma unroll
    for (int of = 0; of < 3; ++of) {
      bf16x8 w = *((const bf16x8*)(wbase + (kt * 24 + ogb + of) * 512));
      #pragma unroll
      for (int jf = 0; jf < 4; ++jf)
        acc[jf][of] = __builtin_amdgcn_mfma_f32_16x16x32_bf16(a[jf], w, acc[jf][of], 0, 0, 0);
    }
  }

  // ---- epilogue: BN + residual, write bf16 stash ----
  const int o0 = oh * 192 + wid * 48;
  #pragma unroll
  for (int of = 0; of < 3; ++of) {
    const int o = o0 + of * 16 + l15;
    const float s = pwg[o] * rsqrtf(pwv[o] + EPS);
    const float t = pwb[o] - pwm[o] * s;
    #pragma unroll
    for (int jf = 0; jf < 4; ++jf) {
      const int j = j0 + jf * 16 + q * 4;
      f32x4 av = acc[jf][of];
      float4 xr = *((const float4*)(xin + bbase + (size_t)o * HW + j));
      ushort4 w4;
      w4.x = f2bf(av[0] * s + t + xr.x);
      w4.y = f2bf(av[1] * s + t + xr.y);
      w4.z = f2bf(av[2] * s + t + xr.z);
      w4.w = f2bf(av[3] * s + t + xr.w);
      size_t pidx = (size_t)(b * CC + o) * SLOT_U + HALF_U + j;
      *((ushort4*)(xpw + pidx)) = w4;
    }
  }
}

// ---------------------------------------------------------------------------
// Fallback path (ws too small): round-2 v2 kernels, verbatim.
// ---------------------------------------------------------------------------
__global__ __launch_bounds__(256) void pack_w_old(
    const float* __restrict__ wmat, unsigned short* __restrict__ wp)
{
  int i = blockIdx.x * 256 + threadIdx.x;
  int kt  = i / WSTEP_U;
  int rem = i - kt * WSTEP_U;
  int o   = rem / WROW;
  int kk  = rem - o * WROW;
  unsigned short v = 0;
  if (kk < 32) v = f2bf(wmat[o * CC + kt * 32 + kk]);
  wp[i] = v;
}

__global__ __launch_bounds__(256, 3) void pw_gemm_bn_res_old(
    const float* __restrict__ xin,
    const unsigned short* __restrict__ wp,
    const float* __restrict__ pwg, const float* __restrict__ pwb,
    const float* __restrict__ pwm, const float* __restrict__ pwv,
    unsigned short* __restrict__ xpw)
{
  __shared__ __align__(16) unsigned short Xt[64 * 40];
  __shared__ __align__(16) unsigned short Wt[WSTEP_U];
  __shared__ float scaleS[CC];
  __shared__ float shiftS[CC];

  const int tid = threadIdx.x;
  const int j0 = blockIdx.x * 64;
  const int b  = blockIdx.y;
  const size_t bbase = (size_t)b * PLANE_ELEMS;

  for (int o = tid; o < CC; o += 256) {
    float s = pwg[o] * rsqrtf(pwv[o] + EPS);
    scaleS[o] = s;
    shiftS[o] = pwb[o] - pwm[o] * s;
  }

  const int lane = tid & 63;
  const int wid  = tid >> 6;
  const int l15  = lane & 15;
  const int q    = lane >> 4;

  f32x4 acc[4][6] = {};
  const float* xsrc0 = xin + bbase + (size_t)(wid * 8) * HW + (j0 + lane);

  for (int kt = 0; kt < 12; ++kt) {
    const int c0 = kt * 32;
    __syncthreads();
    {
      const float* src = xsrc0 + (size_t)c0 * HW;
      float v0 = src[0 * HW], v1 = src[1 * HW], v2 = src[2 * HW], v3 = src[3 * HW];
      float v4 = src[4 * HW], v5 = src[5 * HW], v6 = src[6 * HW], v7 = src[7 * HW];
      bf16x8 u;
      u[0] = (short)f2bf(v0); u[1] = (short)f2bf(v1);
      u[2] = (short)f2bf(v2); u[3] = (short)f2bf(v3);
      u[4] = (short)f2bf(v4); u[5] = (short)f2bf(v5);
      u[6] = (short)f2bf(v6); u[7] = (short)f2bf(v7);
      *((bf16x8*)&Xt[lane * 40 + wid * 8]) = u;
    }
    {
      const unsigned short* g = wp + (size_t)kt * WSTEP_U;
      #pragma unroll
      for (int i = 0; i < 8; ++i) {
        int c = i * 4 + wid;
        if (c < 30) {
          __builtin_amdgcn_global_load_lds(
              (const __attribute__((address_space(1))) unsigned int*)(g + c * 512 + lane * 8),
              (__attribute__((address_space(3))) unsigned int*)(&Wt[c * 512]),
              16, 0, 0);
        }
      }
    }
    __syncthreads();

    bf16x8 a[4];
    #pragma unroll
    for (int jf = 0; jf < 4; ++jf)
      a[jf] = *((const bf16x8*)&Xt[(jf * 16 + l15) * 40 + q * 8]);

    #pragma unroll
    for (int of = 0; of < 6; ++of) {
      bf16x8 bb = *((const bf16x8*)&Wt[(wid * 96 + of * 16 + l15) * WROW + q * 8]);
      #pragma unroll
      for (int jf = 0; jf < 4; ++jf)
        acc[jf][of] = __builtin_amdgcn_mfma_f32_16x16x32_bf16(a[jf], bb, acc[jf][of], 0, 0, 0);
    }
  }

  const int ob = wid * 96;
  #pragma unroll
  for (int of = 0; of < 6; ++of) {
    const int o = ob + of * 16 + l15;
    const float s = scaleS[o], t = shiftS[o];
    #pragma unroll
    for (int jf = 0; jf < 4; ++jf) {
      const int j = j0 + jf * 16 + q * 4;
      f32x4 av = acc[jf][of];
      float4 xr = *((const float4*)(xin + bbase + (size_t)o * HW + j));
      ushort4 w4;
      w4.x = f2bf(av[0] * s + t + xr.x);
      w4.y = f2bf(av[1] * s + t + xr.y);
      w4.z = f2bf(av[2] * s + t + xr.z);
      w4.w = f2bf(av[3] * s + t + xr.w);
      size_t pidx = (size_t)(b * CC + o) * SLOT_U + HALF_U + j;
      *((ushort4*)(xpw + pidx)) = w4;
    }
  }
}

// ---------------------------------------------------------------------------
// Kernel B (MFMA Toeplitz): 13x13 depthwise conv + BN_k + center-tap branch
// + exact GELU, one block per (b,c) plane. (unchanged this round)
// ---------------------------------------------------------------------------
#define TSTRIDE 88
#define TROWS 76
#define NCH 11   // b128 chunks per tile row (88 u16 = 11 * 8)

__global__ __launch_bounds__(256) void dw_conv_mfma(
    float* __restrict__ outf,
    const unsigned short* __restrict__ stash,
    const unsigned short* __restrict__ btg,
    const float* __restrict__ dwkw,
    const float* __restrict__ dkg, const float* __restrict__ dkb,
    const float* __restrict__ dkm, const float* __restrict__ dkv,
    const float* __restrict__ d1w,
    const float* __restrict__ d1g, const float* __restrict__ d1b,
    const float* __restrict__ d1m, const float* __restrict__ d1v)
{
  __shared__ __align__(16) unsigned short tile[TROWS * TSTRIDE];
  __shared__ __align__(16) unsigned short Bt[13 * 16 * 32];

  const int bc = blockIdx.x;
  const int c = bc % CC;
  const size_t plane_u = (size_t)bc * SLOT_U + HALF_U;
  const size_t plane_f = (size_t)bc * HW;
  const int tid = threadIdx.x;
  const int lane = tid & 63;
  const int wid  = tid >> 6;

  for (int i = tid; i < TROWS * NCH; i += 256) {
    int r = i / NCH, ch = i - r * NCH;
    int gy = r - 6;
    bf16x8 v = {0,0,0,0,0,0,0,0};
    if ((unsigned)gy < (unsigned)WIDTH && ch >= 1 && ch <= 7)
      v = *((const bf16x8*)(stash + plane_u + gy * WIDTH + (ch - 1) * 8));
    *((bf16x8*)&tile[r * TSTRIDE + ch * 8]) = v;
  }

  if (btg) {
    const unsigned short* g = btg + (size_t)c * BT_U;
    #pragma unroll
    for (int i = 0; i < 4; ++i) {
      int ch = i * 4 + wid;
      if (ch < 13) {
        __builtin_amdgcn_global_load_lds(
            (const __attribute__((address_space(1))) unsigned int*)(g + ch * 512 + lane * 8),
            (__attribute__((address_space(3))) unsigned int*)(&Bt[ch * 512]),
            16, 0, 0);
      }
    }
  } else {
    for (int i = tid; i < 13 * 512; i += 256) {
      int ky = i >> 9, rem = i & 511, n = rem >> 5, k = rem & 31;
      int kx = k - n - 2;
      float wv = ((unsigned)kx < 13u) ? dwkw[c * 169 + ky * 13 + kx] : 0.f;
      Bt[i] = f2bf(wv);
    }
  }

  const float sk = dkg[c] * rsqrtf(dkv[c] + EPS);
  const float tk = dkb[c] - dkm[c] * sk;
  const float s1 = d1g[c] * rsqrtf(d1v[c] + EPS);
  const float a1 = d1w[c] * s1;
  const float t1 = d1b[c] - d1m[c] * s1;
  const float tsum = tk + t1;

  __syncthreads();

  const int l15  = lane & 15;
  const int q    = lane >> 4;

  bf16x8 bfr[13];
  #pragma unroll
  for (int ky = 0; ky < 13; ++ky)
    bfr[ky] = *((const bf16x8*)&Bt[(ky * 16 + l15) * 32 + q * 8]);

  for (int t = wid; t < 16; t += 4) {
    const int y0 = (t >> 2) * 16, x0 = (t & 3) * 16;
    f32x4 acc = {0.f, 0.f, 0.f, 0.f};
    #pragma unroll
    for (int ky = 0; ky < 13; ++ky) {
      bf16x8 a = *((const bf16x8*)&tile[(y0 + l15 + ky) * TSTRIDE + x0 + q * 8]);
      acc = __builtin_amdgcn_mfma_f32_16x16x32_bf16(a, bfr[ky], acc, 0, 0, 0);
    }
    const int x = x0 + l15;
    if (x < WIDTH) {
      #pragma unroll
      for (int r = 0; r < 4; ++r) {
        const int y = y0 + q * 4 + r;
        if (y < WIDTH) {
          float ctr = bf2f(tile[(y + 6) * TSTRIDE + x + 8]);
          float v = acc[r] * sk + tsum + ctr * a1;
          outf[plane_f + y * WIDTH + x] =
              0.5f * v * (1.f + erff(v * 0.70710678118654752f));
        }
      }
    }
  }
}

extern "C" void kernel_launch(void* const* d_in, const int* in_sizes, int n_in,
                              void* d_out, int out_size, void* d_ws, size_t ws_size,
                              hipStream_t stream) {
  const float* x     = (const float*)d_in[0];
  const float* pw_w  = (const float*)d_in[1];
  const float* pw_g  = (const float*)d_in[2];
  const float* pw_b  = (const float*)d_in[3];
  const float* pw_m  = (const float*)d_in[4];
  const float* pw_v  = (const float*)d_in[5];
  const float* dwk_w = (const float*)d_in[6];
  const float* dwk_g = (const float*)d_in[7];
  const float* dwk_b = (const float*)d_in[8];
  const float* dwk_m = (const float*)d_in[9];
  const float* dwk_v = (const float*)d_in[10];
  const float* dw1_w = (const float*)d_in[11];
  const float* dw1_g = (const float*)d_in[12];
  const float* dw1_b = (const float*)d_in[13];
  const float* dw1_m = (const float*)d_in[14];
  const float* dw1_v = (const float*)d_in[15];
  float* outf = (float*)d_out;
  unsigned short* outu = (unsigned short*)d_out;
  unsigned short* ws = (unsigned short*)d_ws;

  unsigned short* btg = nullptr;

  if (ws_size >= WS_FAST_BYTES) {
    // ---- fast path: fragment-order GEMM, no barriers ----
    unsigned short* wf = ws;
    btg               = ws + WF_U;
    unsigned short* xf = ws + WF_U + BT_TOTAL;

    pack_wf<<<(12*24*64)/256, 256, 0, stream>>>(pw_w, wf);
    pack_bt<<<CC, 256, 0, stream>>>(dwk_w, btg);

    dim3 gridT(12, 49, 16);
    stage_xfrag<<<gridT, 256, 0, stream>>>(x, xf);

    dim3 gridA(49, 2, 16);
    pw_gemm_frag<<<gridA, 256, 0, stream>>>(x, wf, xf, pw_g, pw_b, pw_m, pw_v, outu);
  } else {
    // ---- fallback: round-2 v2 path ----
    unsigned short* wpack = ws;
    pack_w_old<<<WP_TOTAL / 256, 256, 0, stream>>>(pw_w, wpack);
    if (ws_size >= (size_t)(WP_TOTAL + BT_TOTAL) * sizeof(unsigned short)) {
      btg = wpack + WP_TOTAL;
      pack_bt<<<CC, 256, 0, stream>>>(dwk_w, btg);
    }
    dim3 gridA(HW / 64, 16);
    pw_gemm_bn_res_old<<<gridA, 256, 0, stream>>>(x, wpack, pw_g, pw_b, pw_m, pw_v, outu);
  }

  dim3 gridB(16 * CC);
  dw_conv_mfma<<<gridB, 256, 0, stream>>>(outf, outu, btg, dwk_w,
      dwk_g, dwk_b, dwk_m, dwk_v, dw1_w, dw1_g, dw1_b, dw1_m, dw1_v);
}

// Round 5
// 247.800 us; speedup vs baseline: 1.0853x; 1.0265x over previous
//
#include <hip/hip_runtime.h>

#define CC 384
#define HW 3136            // 56*56
#define WIDTH 56
#define PLANE_ELEMS (CC*HW)  // 1204224
#define EPS 1e-5f

// bf16 x_pw for plane p lives in the 2nd half of plane p's f32 output slot:
// ushort index = p*6272 + 3136 + j   (slot = 12544 B = 6272 ushorts)
#define SLOT_U 6272
#define HALF_U 3136

// ---------------- fast-path workspace layout (ushort units) ----------------
// wf  : W in fragment order  [12 kt][24 og][64 lane][8]      = 147456 u
// btg : Toeplitz B per chan  [384 c][13 ky][16 n][32 k]      = 2555904 u
// xf  : x A-fragments        [16 b][49 jt][12 kt][4 jf][64 lane][8]
#define WF_U (12*24*64*8)          // 147456
#define BT_U 6656
#define BT_TOTAL (CC*BT_U)         // 2555904
#define XF_U (16*49*12*4*64*8)     // 19267584
#define WS_FAST_BYTES ((size_t)(WF_U + BT_TOTAL + XF_U) * 2)   // 43,941,888 B

// ---------------- old-path (fallback) W layout ----------------
#define WROW 40
#define WSTEP_U (CC*WROW)        // 15360 ushorts per k-step
#define WP_TOTAL (12*WSTEP_U)    // 184320 ushorts

typedef __attribute__((ext_vector_type(8))) short bf16x8;
typedef __attribute__((ext_vector_type(4))) float f32x4;

static __device__ __forceinline__ float bf2f(unsigned short u) {
  union { unsigned int i; float f; } x; x.i = ((unsigned int)u) << 16; return x.f;
}
static __device__ __forceinline__ unsigned short f2bf(float f) {
  union { float f; unsigned int i; } x; x.f = f;
  unsigned int r = x.i + 0x7fffu + ((x.i >> 16) & 1u);
  return (unsigned short)(r >> 16);
}

// Branch-free exact-form GELU: erf via Abramowitz-Stegun 7.1.26
// (|eps_erf| <= 1.5e-7 -> output error <= ~1e-7*|v|, invisible vs bf16 noise).
// Replaces ROCm erff (multi-branch, ~80 inst with divergence) with ~15 inst.
static __device__ __forceinline__ float gelu_fast(float v) {
  float x  = v * 0.70710678118654752f;
  float ax = fabsf(x);
  float t  = __builtin_amdgcn_rcpf(fmaf(0.3275911f, ax, 1.0f));
  float p  = fmaf(1.061405429f, t, -1.453152027f);
  p = fmaf(p, t, 1.421413741f);
  p = fmaf(p, t, -0.284496736f);
  p = fmaf(p, t, 0.254829592f);
  p = p * t;
  float e  = __expf(-ax * ax);
  float ea = fmaf(-p, e, 1.0f);          // erf(|x|)
  float er = copysignf(ea, x);
  return 0.5f * v * (1.0f + er);
}

// ---------------------------------------------------------------------------
// pack_wf: W f32 -> bf16 directly in MFMA B-fragment order.
// ---------------------------------------------------------------------------
__global__ __launch_bounds__(256) void pack_wf(
    const float* __restrict__ wmat, unsigned short* __restrict__ wf)
{
  int t = blockIdx.x * 256 + threadIdx.x;     // grid = 72 blocks exactly
  int kt  = t / (24 * 64);
  int rem = t - kt * 24 * 64;
  int og  = rem >> 6;
  int lane = rem & 63;
  int o  = og * 16 + (lane & 15);
  int k0 = kt * 32 + (lane >> 4) * 8;
  bf16x8 u;
  #pragma unroll
  for (int i = 0; i < 8; ++i) u[i] = (short)f2bf(wmat[o * CC + k0 + i]);
  *((bf16x8*)(wf + (size_t)t * 8)) = u;
}

// ---------------------------------------------------------------------------
// pack_bt: pre-pack Toeplitz Bt per channel (bf16).
// Bt[c][ky][n][k] = w[c][ky][k-n-2] (matches left-pad-8 tile layout).
// ---------------------------------------------------------------------------
__global__ __launch_bounds__(256) void pack_bt(
    const float* __restrict__ dwkw, unsigned short* __restrict__ btg)
{
  const int c = blockIdx.x;
  for (int i = threadIdx.x; i < BT_U; i += 256) {
    int ky = i >> 9, rem = i & 511, n = rem >> 5, k = rem & 31;
    int kx = k - n - 2;
    unsigned short v = 0;
    if ((unsigned)kx < 13u) v = f2bf(dwkw[c * 169 + ky * 13 + kx]);
    btg[(size_t)c * BT_U + i] = v;
  }
}

// ---------------------------------------------------------------------------
// stage_xfrag: f32 x -> bf16 A-fragments, one (kt, jt, b) tile per block.
// ---------------------------------------------------------------------------
__global__ __launch_bounds__(256) void stage_xfrag(
    const float* __restrict__ xin, unsigned short* __restrict__ xf)
{
  __shared__ __align__(16) unsigned short Xt[64 * 40];   // [j][k], pad 40
  const int kt = blockIdx.x, jt = blockIdx.y, b = blockIdx.z;
  const int tid = threadIdx.x;
  const int lane = tid & 63, wid = tid >> 6;
  const int l15 = lane & 15, q = lane >> 4;

  const float* src = xin + (size_t)b * PLANE_ELEMS
                   + (size_t)(kt * 32 + wid * 8) * HW + jt * 64 + lane;
  bf16x8 u;
  #pragma unroll
  for (int i = 0; i < 8; ++i) u[i] = (short)f2bf(src[(size_t)i * HW]);
  *((bf16x8*)&Xt[lane * 40 + wid * 8]) = u;
  __syncthreads();
  bf16x8 f = *((const bf16x8*)&Xt[(wid * 16 + l15) * 40 + q * 8]);  // jf = wid
  *((bf16x8*)(xf + ((size_t)((b * 49 + jt) * 12 + kt) * 4 + wid) * 512
                 + lane * 8)) = f;
}

// ---------------------------------------------------------------------------
// pw_gemm_frag: barrier-free, LDS-free GEMM + BN + residual -> bf16 stash.
// ---------------------------------------------------------------------------
__global__ __launch_bounds__(256, 3) void pw_gemm_frag(
    const float* __restrict__ xin,
    const unsigned short* __restrict__ wf,
    const unsigned short* __restrict__ xf,
    const float* __restrict__ pwg, const float* __restrict__ pwb,
    const float* __restrict__ pwm, const float* __restrict__ pwv,
    unsigned short* __restrict__ xpw)   // = (ushort*)d_out
{
  const int tid = threadIdx.x;
  const int jt = blockIdx.x, oh = blockIdx.y, b = blockIdx.z;
  const int j0 = jt * 64;
  const int lane = tid & 63, wid = tid >> 6;
  const int l15 = lane & 15, q = lane >> 4;
  const size_t bbase = (size_t)b * PLANE_ELEMS;

  f32x4 acc[4][3] = {};

  const unsigned short* xbase = xf + (size_t)(b * 49 + jt) * (12 * 2048) + lane * 8;
  const unsigned short* wbase = wf + lane * 8;
  const int ogb = oh * 12 + wid * 3;

  #pragma unroll 2
  for (int kt = 0; kt < 12; ++kt) {
    bf16x8 a[4];
    #pragma unroll
    for (int jf = 0; jf < 4; ++jf)
      a[jf] = *((const bf16x8*)(xbase + (kt * 4 + jf) * 512));
    #pragma unroll
    for (int of = 0; of < 3; ++of) {
      bf16x8 w = *((const bf16x8*)(wbase + (kt * 24 + ogb + of) * 512));
      #pragma unroll
      for (int jf = 0; jf < 4; ++jf)
        acc[jf][of] = __builtin_amdgcn_mfma_f32_16x16x32_bf16(a[jf], w, acc[jf][of], 0, 0, 0);
    }
  }

  // ---- epilogue: BN + residual, write bf16 stash ----
  const int o0 = oh * 192 + wid * 48;
  #pragma unroll
  for (int of = 0; of < 3; ++of) {
    const int o = o0 + of * 16 + l15;
    const float s = pwg[o] * rsqrtf(pwv[o] + EPS);
    const float t = pwb[o] - pwm[o] * s;
    #pragma unroll
    for (int jf = 0; jf < 4; ++jf) {
      const int j = j0 + jf * 16 + q * 4;
      f32x4 av = acc[jf][of];
      float4 xr = *((const float4*)(xin + bbase + (size_t)o * HW + j));
      ushort4 w4;
      w4.x = f2bf(av[0] * s + t + xr.x);
      w4.y = f2bf(av[1] * s + t + xr.y);
      w4.z = f2bf(av[2] * s + t + xr.z);
      w4.w = f2bf(av[3] * s + t + xr.w);
      size_t pidx = (size_t)(b * CC + o) * SLOT_U + HALF_U + j;
      *((ushort4*)(xpw + pidx)) = w4;
    }
  }
}

// ---------------------------------------------------------------------------
// Fallback path (ws too small): round-2 v2 kernels, verbatim.
// ---------------------------------------------------------------------------
__global__ __launch_bounds__(256) void pack_w_old(
    const float* __restrict__ wmat, unsigned short* __restrict__ wp)
{
  int i = blockIdx.x * 256 + threadIdx.x;
  int kt  = i / WSTEP_U;
  int rem = i - kt * WSTEP_U;
  int o   = rem / WROW;
  int kk  = rem - o * WROW;
  unsigned short v = 0;
  if (kk < 32) v = f2bf(wmat[o * CC + kt * 32 + kk]);
  wp[i] = v;
}

__global__ __launch_bounds__(256, 3) void pw_gemm_bn_res_old(
    const float* __restrict__ xin,
    const unsigned short* __restrict__ wp,
    const float* __restrict__ pwg, const float* __restrict__ pwb,
    const float* __restrict__ pwm, const float* __restrict__ pwv,
    unsigned short* __restrict__ xpw)
{
  __shared__ __align__(16) unsigned short Xt[64 * 40];
  __shared__ __align__(16) unsigned short Wt[WSTEP_U];
  __shared__ float scaleS[CC];
  __shared__ float shiftS[CC];

  const int tid = threadIdx.x;
  const int j0 = blockIdx.x * 64;
  const int b  = blockIdx.y;
  const size_t bbase = (size_t)b * PLANE_ELEMS;

  for (int o = tid; o < CC; o += 256) {
    float s = pwg[o] * rsqrtf(pwv[o] + EPS);
    scaleS[o] = s;
    shiftS[o] = pwb[o] - pwm[o] * s;
  }

  const int lane = tid & 63;
  const int wid  = tid >> 6;
  const int l15  = lane & 15;
  const int q    = lane >> 4;

  f32x4 acc[4][6] = {};
  const float* xsrc0 = xin + bbase + (size_t)(wid * 8) * HW + (j0 + lane);

  for (int kt = 0; kt < 12; ++kt) {
    const int c0 = kt * 32;
    __syncthreads();
    {
      const float* src = xsrc0 + (size_t)c0 * HW;
      float v0 = src[0 * HW], v1 = src[1 * HW], v2 = src[2 * HW], v3 = src[3 * HW];
      float v4 = src[4 * HW], v5 = src[5 * HW], v6 = src[6 * HW], v7 = src[7 * HW];
      bf16x8 u;
      u[0] = (short)f2bf(v0); u[1] = (short)f2bf(v1);
      u[2] = (short)f2bf(v2); u[3] = (short)f2bf(v3);
      u[4] = (short)f2bf(v4); u[5] = (short)f2bf(v5);
      u[6] = (short)f2bf(v6); u[7] = (short)f2bf(v7);
      *((bf16x8*)&Xt[lane * 40 + wid * 8]) = u;
    }
    {
      const unsigned short* g = wp + (size_t)kt * WSTEP_U;
      #pragma unroll
      for (int i = 0; i < 8; ++i) {
        int c = i * 4 + wid;
        if (c < 30) {
          __builtin_amdgcn_global_load_lds(
              (const __attribute__((address_space(1))) unsigned int*)(g + c * 512 + lane * 8),
              (__attribute__((address_space(3))) unsigned int*)(&Wt[c * 512]),
              16, 0, 0);
        }
      }
    }
    __syncthreads();

    bf16x8 a[4];
    #pragma unroll
    for (int jf = 0; jf < 4; ++jf)
      a[jf] = *((const bf16x8*)&Xt[(jf * 16 + l15) * 40 + q * 8]);

    #pragma unroll
    for (int of = 0; of < 6; ++of) {
      bf16x8 bb = *((const bf16x8*)&Wt[(wid * 96 + of * 16 + l15) * WROW + q * 8]);
      #pragma unroll
      for (int jf = 0; jf < 4; ++jf)
        acc[jf][of] = __builtin_amdgcn_mfma_f32_16x16x32_bf16(a[jf], bb, acc[jf][of], 0, 0, 0);
    }
  }

  const int ob = wid * 96;
  #pragma unroll
  for (int of = 0; of < 6; ++of) {
    const int o = ob + of * 16 + l15;
    const float s = scaleS[o], t = shiftS[o];
    #pragma unroll
    for (int jf = 0; jf < 4; ++jf) {
      const int j = j0 + jf * 16 + q * 4;
      f32x4 av = acc[jf][of];
      float4 xr = *((const float4*)(xin + bbase + (size_t)o * HW + j));
      ushort4 w4;
      w4.x = f2bf(av[0] * s + t + xr.x);
      w4.y = f2bf(av[1] * s + t + xr.y);
      w4.z = f2bf(av[2] * s + t + xr.z);
      w4.w = f2bf(av[3] * s + t + xr.w);
      size_t pidx = (size_t)(b * CC + o) * SLOT_U + HALF_U + j;
      *((ushort4*)(xpw + pidx)) = w4;
    }
  }
}

// ---------------------------------------------------------------------------
// Kernel B (MFMA Toeplitz): 13x13 depthwise conv + BN_k + center-tap branch
// + GELU, one block per (b,c) plane.
// Round-4 change: erff (multi-branch, divergent, ~80 inst) -> gelu_fast
// (branch-free A&S erf, ~15 inst). Kernel was VALU-issue-bound (VALUBusy 69%).
// ---------------------------------------------------------------------------
#define TSTRIDE 88
#define TROWS 76
#define NCH 11   // b128 chunks per tile row (88 u16 = 11 * 8)

__global__ __launch_bounds__(256) void dw_conv_mfma(
    float* __restrict__ outf,
    const unsigned short* __restrict__ stash,
    const unsigned short* __restrict__ btg,
    const float* __restrict__ dwkw,
    const float* __restrict__ dkg, const float* __restrict__ dkb,
    const float* __restrict__ dkm, const float* __restrict__ dkv,
    const float* __restrict__ d1w,
    const float* __restrict__ d1g, const float* __restrict__ d1b,
    const float* __restrict__ d1m, const float* __restrict__ d1v)
{
  __shared__ __align__(16) unsigned short tile[TROWS * TSTRIDE];
  __shared__ __align__(16) unsigned short Bt[13 * 16 * 32];

  const int bc = blockIdx.x;
  const int c = bc % CC;
  const size_t plane_u = (size_t)bc * SLOT_U + HALF_U;
  const size_t plane_f = (size_t)bc * HW;
  const int tid = threadIdx.x;
  const int lane = tid & 63;
  const int wid  = tid >> 6;

  for (int i = tid; i < TROWS * NCH; i += 256) {
    int r = i / NCH, ch = i - r * NCH;
    int gy = r - 6;
    bf16x8 v = {0,0,0,0,0,0,0,0};
    if ((unsigned)gy < (unsigned)WIDTH && ch >= 1 && ch <= 7)
      v = *((const bf16x8*)(stash + plane_u + gy * WIDTH + (ch - 1) * 8));
    *((bf16x8*)&tile[r * TSTRIDE + ch * 8]) = v;
  }

  if (btg) {
    const unsigned short* g = btg + (size_t)c * BT_U;
    #pragma unroll
    for (int i = 0; i < 4; ++i) {
      int ch = i * 4 + wid;
      if (ch < 13) {
        __builtin_amdgcn_global_load_lds(
            (const __attribute__((address_space(1))) unsigned int*)(g + ch * 512 + lane * 8),
            (__attribute__((address_space(3))) unsigned int*)(&Bt[ch * 512]),
            16, 0, 0);
      }
    }
  } else {
    for (int i = tid; i < 13 * 512; i += 256) {
      int ky = i >> 9, rem = i & 511, n = rem >> 5, k = rem & 31;
      int kx = k - n - 2;
      float wv = ((unsigned)kx < 13u) ? dwkw[c * 169 + ky * 13 + kx] : 0.f;
      Bt[i] = f2bf(wv);
    }
  }

  const float sk = dkg[c] * rsqrtf(dkv[c] + EPS);
  const float tk = dkb[c] - dkm[c] * sk;
  const float s1 = d1g[c] * rsqrtf(d1v[c] + EPS);
  const float a1 = d1w[c] * s1;
  const float t1 = d1b[c] - d1m[c] * s1;
  const float tsum = tk + t1;

  __syncthreads();

  const int l15  = lane & 15;
  const int q    = lane >> 4;

  bf16x8 bfr[13];
  #pragma unroll
  for (int ky = 0; ky < 13; ++ky)
    bfr[ky] = *((const bf16x8*)&Bt[(ky * 16 + l15) * 32 + q * 8]);

  for (int t = wid; t < 16; t += 4) {
    const int y0 = (t >> 2) * 16, x0 = (t & 3) * 16;
    f32x4 acc = {0.f, 0.f, 0.f, 0.f};
    #pragma unroll
    for (int ky = 0; ky < 13; ++ky) {
      bf16x8 a = *((const bf16x8*)&tile[(y0 + l15 + ky) * TSTRIDE + x0 + q * 8]);
      acc = __builtin_amdgcn_mfma_f32_16x16x32_bf16(a, bfr[ky], acc, 0, 0, 0);
    }
    const int x = x0 + l15;
    if (x < WIDTH) {
      #pragma unroll
      for (int r = 0; r < 4; ++r) {
        const int y = y0 + q * 4 + r;
        if (y < WIDTH) {
          float ctr = bf2f(tile[(y + 6) * TSTRIDE + x + 8]);
          float v = acc[r] * sk + tsum + ctr * a1;
          outf[plane_f + y * WIDTH + x] = gelu_fast(v);
        }
      }
    }
  }
}

extern "C" void kernel_launch(void* const* d_in, const int* in_sizes, int n_in,
                              void* d_out, int out_size, void* d_ws, size_t ws_size,
                              hipStream_t stream) {
  const float* x     = (const float*)d_in[0];
  const float* pw_w  = (const float*)d_in[1];
  const float* pw_g  = (const float*)d_in[2];
  const float* pw_b  = (const float*)d_in[3];
  const float* pw_m  = (const float*)d_in[4];
  const float* pw_v  = (const float*)d_in[5];
  const float* dwk_w = (const float*)d_in[6];
  const float* dwk_g = (const float*)d_in[7];
  const float* dwk_b = (const float*)d_in[8];
  const float* dwk_m = (const float*)d_in[9];
  const float* dwk_v = (const float*)d_in[10];
  const float* dw1_w = (const float*)d_in[11];
  const float* dw1_g = (const float*)d_in[12];
  const float* dw1_b = (const float*)d_in[13];
  const float* dw1_m = (const float*)d_in[14];
  const float* dw1_v = (const float*)d_in[15];
  float* outf = (float*)d_out;
  unsigned short* outu = (unsigned short*)d_out;
  unsigned short* ws = (unsigned short*)d_ws;

  unsigned short* btg = nullptr;

  if (ws_size >= WS_FAST_BYTES) {
    // ---- fast path: fragment-order GEMM, no barriers ----
    unsigned short* wf = ws;
    btg               = ws + WF_U;
    unsigned short* xf = ws + WF_U + BT_TOTAL;

    pack_wf<<<(12*24*64)/256, 256, 0, stream>>>(pw_w, wf);
    pack_bt<<<CC, 256, 0, stream>>>(dwk_w, btg);

    dim3 gridT(12, 49, 16);
    stage_xfrag<<<gridT, 256, 0, stream>>>(x, xf);

    dim3 gridA(49, 2, 16);
    pw_gemm_frag<<<gridA, 256, 0, stream>>>(x, wf, xf, pw_g, pw_b, pw_m, pw_v, outu);
  } else {
    // ---- fallback: round-2 v2 path ----
    unsigned short* wpack = ws;
    pack_w_old<<<WP_TOTAL / 256, 256, 0, stream>>>(pw_w, wpack);
    if (ws_size >= (size_t)(WP_TOTAL + BT_TOTAL) * sizeof(unsigned short)) {
      btg = wpack + WP_TOTAL;
      pack_bt<<<CC, 256, 0, stream>>>(dwk_w, btg);
    }
    dim3 gridA(HW / 64, 16);
    pw_gemm_bn_res_old<<<gridA, 256, 0, stream>>>(x, wpack, pw_g, pw_b, pw_m, pw_v, outu);
  }

  dim3 gridB(16 * CC);
  dw_conv_mfma<<<gridB, 256, 0, stream>>>(outf, outu, btg, dwk_w,
      dwk_g, dwk_b, dwk_m, dwk_v, dw1_w, dw1_g, dw1_b, dw1_m, dw1_v);
}